// Round 1
// baseline (254.882 us; speedup 1.0000x reference)
//
#include <hip/hip_runtime.h>
#include <hip/hip_bf16.h>

#define BB 8
#define SQ 2048
#define SK 2048
#define DD 128
#define NEGV -1.0e9f
#define INV_TEMPER 0.08838834764831845f  // 1/sqrt(128)

using s16x8 = __attribute__((ext_vector_type(8))) short;
using f32x4 = __attribute__((ext_vector_type(4))) float;

__device__ __forceinline__ unsigned short f2bf(float f) {
  union { float f; unsigned u; } v; v.f = f;
  unsigned r = v.u + 0x7FFFu + ((v.u >> 16) & 1u);
  return (unsigned short)(r >> 16);
}

// Kernel 1: raw scores S = QK^T * inv_temper + NEG*(1-mask) -> sbuf (attn region, scratch)
__global__ __launch_bounds__(256) void qk_kernel(
    const float* __restrict__ q, const float* __restrict__ kmat,
    const int* __restrict__ mask, float* __restrict__ sbuf) {
  constexpr int LDK = 136;  // bf16 elems per row (pad: 272B stride, breaks 32-way conflicts)
  __shared__ __align__(16) unsigned short k_lds[64 * LDK];
  const int tid = threadIdx.x;
  const int bid = blockIdx.x;
  const int qt = bid & 127;     // SQ/16 = 128 q-tiles
  const int b  = bid >> 7;
  const int q0 = qt << 4;
  const int lane = tid & 63;
  const int w    = tid >> 6;    // wave 0..3
  const int lrow = lane & 15;   // A-row / B-col
  const int lk   = lane >> 4;   // k-group

  // Q A-fragments in registers: 4 ksteps of 32 over D=128 (reused across all 32 K-tiles)
  s16x8 afrag[4];
  {
    const float* qp = q + ((size_t)(b * SQ + q0 + lrow)) * DD;
    for (int ks = 0; ks < 4; ++ks) {
      const float* s = qp + ks * 32 + lk * 8;
      s16x8 a;
      for (int j = 0; j < 8; ++j) a[j] = (short)f2bf(s[j]);
      afrag[ks] = a;
    }
  }

  for (int t = 0; t < 32; ++t) {
    const int kr0 = t << 6;
    // stage K tile (64 rows x 128 d) as bf16, coalesced float4 global reads
    for (int i = 0; i < 8; ++i) {
      int idx4 = tid + (i << 8);
      int row = idx4 >> 5;
      int dq  = (idx4 & 31) << 2;
      const float4 vv = *(const float4*)(kmat + ((size_t)(b * SK + kr0 + row)) * DD + dq);
      ushort4 pk;
      pk.x = f2bf(vv.x); pk.y = f2bf(vv.y); pk.z = f2bf(vv.z); pk.w = f2bf(vv.w);
      *(ushort4*)(&k_lds[row * LDK + dq]) = pk;
    }
    __syncthreads();

    f32x4 acc = {0.f, 0.f, 0.f, 0.f};
    for (int ks = 0; ks < 4; ++ks) {
      s16x8 bfrag = *(const s16x8*)(&k_lds[(w * 16 + lrow) * LDK + ks * 32 + lk * 8]);
      acc = __builtin_amdgcn_mfma_f32_16x16x32_bf16(afrag[ks], bfrag, acc, 0, 0, 0);
    }

    const int col = kr0 + (w << 4) + lrow;
    for (int r = 0; r < 4; ++r) {
      const int row = q0 + (lk << 2) + r;
      const size_t off = ((size_t)(b * SQ + row)) * SK + col;
      sbuf[off] = acc[r] * INV_TEMPER + NEGV * (1.0f - (float)mask[off]);
    }
    __syncthreads();
  }
}

// Kernel 2: softmax (stats + normalize, probs -> attn region in-place) + PV -> out
__global__ __launch_bounds__(256) void smpv_kernel(
    float* sb /* raw S in, probs out (same buffer) */,
    const float* __restrict__ v, float* __restrict__ outp) {
  constexpr int LDV = 72;  // bf16 stride (144B rows: ~2-way banks on b128 reads)
  __shared__ __align__(16) unsigned short vT[128 * LDV];   // V transposed [d][k]
  __shared__ __align__(16) unsigned short p_lds[16 * LDV]; // P tile [qrow][k]
  __shared__ float m_s[16], il_s[16];
  const int tid = threadIdx.x;
  const int bid = blockIdx.x;
  const int qt = bid & 127;
  const int b  = bid >> 7;
  const int q0 = qt << 4;
  const int lane = tid & 63;
  const int w    = tid >> 6;
  const int lrow = lane & 15;
  const int lk   = lane >> 4;
  const int lr = tid >> 4;   // local q-row 0..15
  const int cg = tid & 15;   // col-group within row

  // Phase A: per-row online max + sumexp over the full 2048-col raw-S row
  {
    const float* srow = sb + ((size_t)(b * SQ + q0 + lr)) * SK;
    float m = -INFINITY, l = 0.f;
    for (int i = 0; i < 32; ++i) {
      const float4 s4 = *(const float4*)(srow + (cg << 2) + (i << 6));
      float t4 = fmaxf(fmaxf(s4.x, s4.y), fmaxf(s4.z, s4.w));
      float nm = fmaxf(m, t4);
      l = l * __expf(m - nm) + __expf(s4.x - nm) + __expf(s4.y - nm)
        + __expf(s4.z - nm) + __expf(s4.w - nm);
      m = nm;
    }
    for (int d = 1; d < 16; d <<= 1) {
      float mo = __shfl_xor(m, d);
      float lo = __shfl_xor(l, d);
      float nm = fmaxf(m, mo);
      l = l * __expf(m - nm) + lo * __expf(mo - nm);
      m = nm;
    }
    if (cg == 0) { m_s[lr] = m; il_s[lr] = 1.0f / l; }
  }
  __syncthreads();

  f32x4 acc[2];
  acc[0] = f32x4{0.f, 0.f, 0.f, 0.f};
  acc[1] = f32x4{0.f, 0.f, 0.f, 0.f};

  const int jv = tid & 63;   // v-row within tile
  const int dg = tid >> 6;   // d-group (32 d each)

  for (int t = 0; t < 32; ++t) {
    const int kr0 = t << 6;
    // stage V^T tile: vT[d][j] (conflict-free LDS writes; global reads ride L2 lines)
    {
      const float* vp = v + ((size_t)(b * SK + kr0 + jv)) * DD + dg * 32;
      for (int i = 0; i < 8; ++i) {
        const float4 vv = *(const float4*)(vp + (i << 2));
        const int d0 = dg * 32 + (i << 2);
        vT[(d0 + 0) * LDV + jv] = f2bf(vv.x);
        vT[(d0 + 1) * LDV + jv] = f2bf(vv.y);
        vT[(d0 + 2) * LDV + jv] = f2bf(vv.z);
        vT[(d0 + 3) * LDV + jv] = f2bf(vv.w);
      }
    }
    // normalize S tile -> attn (fp32, in place) + p_lds (bf16)
    {
      float* sp = sb + ((size_t)(b * SQ + q0 + lr)) * SK + kr0 + (cg << 2);
      float4 s4 = *(const float4*)sp;
      const float m = m_s[lr], il = il_s[lr];
      float4 p4;
      p4.x = __expf(s4.x - m) * il;
      p4.y = __expf(s4.y - m) * il;
      p4.z = __expf(s4.z - m) * il;
      p4.w = __expf(s4.w - m) * il;
      *(float4*)sp = p4;
      ushort4 pk;
      pk.x = f2bf(p4.x); pk.y = f2bf(p4.y); pk.z = f2bf(p4.z); pk.w = f2bf(p4.w);
      *(ushort4*)(&p_lds[lr * LDV + (cg << 2)]) = pk;
    }
    __syncthreads();
    // PV: P[16x64] x V[64x128]; wave w owns output cols w*32..w*32+31
    for (int ks = 0; ks < 2; ++ks) {
      s16x8 af = *(const s16x8*)(&p_lds[lrow * LDV + ks * 32 + lk * 8]);
      for (int nt = 0; nt < 2; ++nt) {
        s16x8 bf = *(const s16x8*)(&vT[((w << 5) + (nt << 4) + lrow) * LDV + ks * 32 + lk * 8]);
        acc[nt] = __builtin_amdgcn_mfma_f32_16x16x32_bf16(af, bf, acc[nt], 0, 0, 0);
      }
    }
    __syncthreads();
  }

  // epilogue: out[16][128]
  for (int nt = 0; nt < 2; ++nt) {
    const int col = (w << 5) + (nt << 4) + lrow;
    for (int r = 0; r < 4; ++r) {
      const int row = q0 + (lk << 2) + r;
      outp[((size_t)(b * SQ + row)) * DD + col] = acc[nt][r];
    }
  }
}

extern "C" void kernel_launch(void* const* d_in, const int* in_sizes, int n_in,
                              void* d_out, int out_size, void* d_ws, size_t ws_size,
                              hipStream_t stream) {
  const float* q = (const float*)d_in[0];
  const float* k = (const float*)d_in[1];
  const float* v = (const float*)d_in[2];
  const int* mask = (const int*)d_in[3];
  float* outp = (float*)d_out;
  float* attn = outp + (size_t)BB * SQ * DD;  // second tuple output; also raw-S scratch

  const int blocks = BB * (SQ / 16);  // 1024
  qk_kernel<<<blocks, 256, 0, stream>>>(q, k, mask, attn);
  smpv_kernel<<<blocks, 256, 0, stream>>>(attn, v, outp);
}